// Round 5
// baseline (1797.712 us; speedup 1.0000x reference)
//
#include <hip/hip_runtime.h>

#define N_NODES 50000
#define N_EDGES 600000
#define N_GRAPHS 500
#define F 128
#define F4 (F/4)

// ================= CSR build =================
__global__ __launch_bounds__(256) void k_hist(const int* __restrict__ dst, int* __restrict__ cnt, int ne) {
    int e = blockIdx.x * 256 + threadIdx.x;
    if (e < ne) atomicAdd(&cnt[dst[e]], 1);
}

__global__ __launch_bounds__(256) void k_scan1(const int* __restrict__ cnt, int* __restrict__ row_ptr,
                                               int* __restrict__ blksums, float* __restrict__ dinv, int n) {
    __shared__ int s[256];
    int i = blockIdx.x * 256 + threadIdx.x;
    int v = (i < n) ? cnt[i] : 0;
    if (i < n) dinv[i] = rsqrtf((float)(v + 1));   // self-loop included
    s[threadIdx.x] = v;
    __syncthreads();
    for (int off = 1; off < 256; off <<= 1) {
        int t = (threadIdx.x >= off) ? s[threadIdx.x - off] : 0;
        __syncthreads();
        s[threadIdx.x] += t;
        __syncthreads();
    }
    if (i < n) row_ptr[i] = s[threadIdx.x] - v;
    if (threadIdx.x == 255) blksums[blockIdx.x] = s[255];
}

__global__ __launch_bounds__(256) void k_scan2(int* __restrict__ blksums, int nb) {
    __shared__ int s[256];
    int v = (threadIdx.x < nb) ? blksums[threadIdx.x] : 0;
    s[threadIdx.x] = v;
    __syncthreads();
    for (int off = 1; off < 256; off <<= 1) {
        int t = (threadIdx.x >= off) ? s[threadIdx.x - off] : 0;
        __syncthreads();
        s[threadIdx.x] += t;
        __syncthreads();
    }
    if (threadIdx.x < nb) blksums[threadIdx.x] = s[threadIdx.x] - v;
}

__global__ __launch_bounds__(256) void k_scan3(int* __restrict__ row_ptr, const int* __restrict__ blksums,
                                               int n, int ne) {
    int i = blockIdx.x * 256 + threadIdx.x;
    if (i < n) row_ptr[i] += blksums[blockIdx.x];
    if (i == 0) row_ptr[n] = ne;
}

// count-down fill: cnt holds degrees on entry (consumed here)
__global__ __launch_bounds__(256) void k_fill(const int* __restrict__ src, const int* __restrict__ dst,
                                              const int* __restrict__ row_ptr, int* __restrict__ cnt,
                                              int* __restrict__ esrc, int ne) {
    int e = blockIdx.x * 256 + threadIdx.x;
    if (e < ne) {
        int d = dst[e];
        int pos = row_ptr[d] + atomicSub(&cnt[d], 1) - 1;
        esrc[pos] = src[e];
    }
}

// ================= GEMM: T = X @ W (X:[n,128], W:[128,128]) =================
#define TM 64
#define FMA4(A, S, Wv) { A.x = fmaf(S, Wv.x, A.x); A.y = fmaf(S, Wv.y, A.y); \
                         A.z = fmaf(S, Wv.z, A.z); A.w = fmaf(S, Wv.w, A.w); }

__global__ __launch_bounds__(256) void k_gemm128(const float* __restrict__ X,
                                                 const float* __restrict__ W,
                                                 float* __restrict__ T, int n_rows) {
    __shared__ float Xs[32 * TM];   // [kk][row]
    __shared__ float Ws[32 * F];    // [kk][col]
    int tid  = threadIdx.x;
    int row0 = blockIdx.x * TM;
    int cg = tid & 15;
    int rg = tid >> 4;
    int j0 = cg * 4;
    int r0 = rg * 4;
    int srow = tid >> 2;
    int skb  = (tid & 3) * 8;
    bool rvalid = (row0 + srow) < n_rows;
    const float* Xrow = X + (size_t)(row0 + srow) * F;

    float4 accA[4], accB[4];
    #pragma unroll
    for (int i = 0; i < 4; i++) { accA[i] = make_float4(0,0,0,0); accB[i] = make_float4(0,0,0,0); }

    for (int kc = 0; kc < 4; ++kc) {
        __syncthreads();
        #pragma unroll
        for (int q = 0; q < 4; ++q) {
            int i = tid + 256 * q;
            ((float4*)Ws)[i] = ((const float4*)(W + (size_t)kc * 32 * F))[i];
        }
        float4 xv0 = make_float4(0,0,0,0), xv1 = make_float4(0,0,0,0);
        if (rvalid) {
            xv0 = ((const float4*)(Xrow + kc * 32 + skb))[0];
            xv1 = ((const float4*)(Xrow + kc * 32 + skb))[1];
        }
        Xs[(skb + 0) * TM + srow] = xv0.x;
        Xs[(skb + 1) * TM + srow] = xv0.y;
        Xs[(skb + 2) * TM + srow] = xv0.z;
        Xs[(skb + 3) * TM + srow] = xv0.w;
        Xs[(skb + 4) * TM + srow] = xv1.x;
        Xs[(skb + 5) * TM + srow] = xv1.y;
        Xs[(skb + 6) * TM + srow] = xv1.z;
        Xs[(skb + 7) * TM + srow] = xv1.w;
        __syncthreads();
        #pragma unroll
        for (int kk = 0; kk < 32; ++kk) {
            float4 xa = *(const float4*)&Xs[kk * TM + r0];
            float4 wa = *(const float4*)&Ws[kk * F + j0];
            float4 wb = *(const float4*)&Ws[kk * F + j0 + 64];
            FMA4(accA[0], xa.x, wa); FMA4(accB[0], xa.x, wb);
            FMA4(accA[1], xa.y, wa); FMA4(accB[1], xa.y, wb);
            FMA4(accA[2], xa.z, wa); FMA4(accB[2], xa.z, wb);
            FMA4(accA[3], xa.w, wa); FMA4(accB[3], xa.w, wb);
        }
    }
    #pragma unroll
    for (int i = 0; i < 4; ++i) {
        int row = row0 + r0 + i;
        if (row < n_rows) {
            ((float4*)(T + (size_t)row * F))[cg]      = accA[i];
            ((float4*)(T + (size_t)row * F))[cg + 16] = accB[i];
        }
    }
}

// ============ edge-parallel gather with LDS accumulation ============
// Block owns NB=64 consecutive dst nodes and ALL their CSR edges (no straddling).
// 16 groups of 16 lanes stream independent edges -> LDS fp32 atomics.
// Finalize fuses self-loop + bias + ReLU.
#define NB 64
#define MAXE 1280

__global__ __launch_bounds__(256) void k_gather(const int* __restrict__ row_ptr,
                                                const int* __restrict__ esrc,
                                                const float* __restrict__ dinv,
                                                const float* __restrict__ T,
                                                const float* __restrict__ bias,
                                                float* __restrict__ H, int n) {
    __shared__ float accum[NB * F];          // 32 KB
    __shared__ int rp[NB + 1];
    __shared__ float dd_l[NB];
    __shared__ unsigned char edst[MAXE];
    int tid = threadIdx.x;
    int d0 = blockIdx.x * NB;

    // zero accumulator (2048 float4)
    #pragma unroll
    for (int j = 0; j < 8; ++j)
        ((float4*)accum)[tid + 256 * j] = make_float4(0.f, 0.f, 0.f, 0.f);

    if (tid <= NB) {
        int d = d0 + tid;
        rp[tid] = row_ptr[d <= n ? d : n];
    }
    if (tid < NB) {
        int d = d0 + tid;
        dd_l[tid] = (d < n) ? dinv[d] : 0.f;
    }
    __syncthreads();
    int e0 = rp[0], e1 = rp[NB];

    // local dst index per edge
    if (tid < NB) {
        int lo = rp[tid] - e0, hi = rp[tid + 1] - e0;
        if (hi > MAXE) hi = MAXE;
        for (int o = lo; o < hi; ++o) edst[o] = (unsigned char)tid;
    }
    __syncthreads();

    int g   = tid >> 4;    // group 0..15
    int sub = tid & 15;
    for (int e = e0 + g; e < e1; e += 16) {
        int off = e - e0;
        int t;
        if (off < MAXE) t = edst[off];
        else {          // ultra-rare fallback: binary search rp
            int lo = 0, hi = NB;
            while (lo + 1 < hi) { int mid = (lo + hi) >> 1; if (rp[mid] <= e) lo = mid; else hi = mid; }
            t = lo;
        }
        int s = esrc[e];
        float w = dinv[s] * dd_l[t];
        const float4* rowp = (const float4*)(T + (size_t)s * F);
        float4 a = rowp[sub], b = rowp[sub + 16];
        float* ac = accum + t * F + 4 * sub;
        atomicAdd(ac + 0,  a.x * w);
        atomicAdd(ac + 1,  a.y * w);
        atomicAdd(ac + 2,  a.z * w);
        atomicAdd(ac + 3,  a.w * w);
        atomicAdd(ac + 64, b.x * w);
        atomicAdd(ac + 65, b.y * w);
        atomicAdd(ac + 66, b.z * w);
        atomicAdd(ac + 67, b.w * w);
    }
    __syncthreads();

    // finalize: H[node] = relu(accum + T[node]*dd^2 + bias)
    #pragma unroll
    for (int j = 0; j < 8; ++j) {
        int lin = tid + 256 * j;       // float4 index within block tile
        int nl = lin >> 5, m = lin & 31;
        int node = d0 + nl;
        if (node < n) {
            float ddv = dd_l[nl];
            float ws = ddv * ddv;
            float4 acc = ((float4*)(accum + nl * F))[m];
            float4 tv  = ((const float4*)(T + (size_t)node * F))[m];
            float4 bb  = ((const float4*)bias)[m];
            float4 r;
            r.x = fmaxf(fmaf(tv.x, ws, acc.x) + bb.x, 0.f);
            r.y = fmaxf(fmaf(tv.y, ws, acc.y) + bb.y, 0.f);
            r.z = fmaxf(fmaf(tv.z, ws, acc.z) + bb.z, 0.f);
            r.w = fmaxf(fmaf(tv.w, ws, acc.w) + bb.w, 0.f);
            ((float4*)(H + (size_t)node * F))[m] = r;
        }
    }
}

// ============ fused pool (segment mean) + FC head ============
__global__ __launch_bounds__(256) void k_pool_fc(const float* __restrict__ H,
                                                 const int* __restrict__ batch,
                                                 const float* __restrict__ Wf1,
                                                 const float* __restrict__ bf1,
                                                 const float* __restrict__ Wf2,
                                                 const float* __restrict__ bf2,
                                                 float* __restrict__ out) {
    int g = blockIdx.x;
    int tid = threadIdx.x;
    int lo = 0, hi = N_NODES;
    while (lo < hi) { int mid = (lo + hi) >> 1; if (batch[mid] < g) lo = mid + 1; else hi = mid; }
    int start = lo;
    hi = N_NODES;
    while (lo < hi) { int mid = (lo + hi) >> 1; if (batch[mid] <= g) lo = mid + 1; else hi = mid; }
    int end = lo;

    __shared__ float hs[4][F];
    __shared__ float hg[F];
    int wv = tid >> 6, lane = tid & 63;
    int half = lane >> 5, sub = lane & 31;
    float4 a = make_float4(0.f, 0.f, 0.f, 0.f);
    for (int i = start + wv * 2 + half; i < end; i += 8) {
        float4 v = ((const float4*)(H + (size_t)i * F))[sub];
        a.x += v.x; a.y += v.y; a.z += v.z; a.w += v.w;
    }
    a.x += __shfl_xor(a.x, 32, 64);
    a.y += __shfl_xor(a.y, 32, 64);
    a.z += __shfl_xor(a.z, 32, 64);
    a.w += __shfl_xor(a.w, 32, 64);
    if (half == 0) ((float4*)hs[wv])[sub] = a;
    __syncthreads();
    if (tid < F) {
        float inv = 1.0f / (float)((end - start) > 0 ? (end - start) : 1);
        hg[tid] = (hs[0][tid] + hs[1][tid] + hs[2][tid] + hs[3][tid]) * inv;
    }
    __syncthreads();
    if (tid < 64) {
        float acc = bf1[tid];
        #pragma unroll 4
        for (int f = 0; f < F; ++f) acc = fmaf(hg[f], Wf1[f * 64 + tid], acc);
        float v = fmaxf(acc, 0.f) * Wf2[tid];
        #pragma unroll
        for (int off = 32; off > 0; off >>= 1) v += __shfl_down(v, off, 64);
        if (tid == 0) out[g] = v + bf2[0];
    }
}

extern "C" void kernel_launch(void* const* d_in, const int* in_sizes, int n_in,
                              void* d_out, int out_size, void* d_ws, size_t ws_size,
                              hipStream_t stream) {
    const float* x    = (const float*)d_in[0];
    const int* eidx   = (const int*)d_in[1];
    const int* batch  = (const int*)d_in[2];
    const float* W1   = (const float*)d_in[3];
    const float* b1   = (const float*)d_in[4];
    const float* W2   = (const float*)d_in[5];
    const float* b2   = (const float*)d_in[6];
    const float* W3   = (const float*)d_in[7];
    const float* b3   = (const float*)d_in[8];
    const float* Wf1  = (const float*)d_in[9];
    const float* bf1  = (const float*)d_in[10];
    const float* Wf2  = (const float*)d_in[11];
    const float* bf2  = (const float*)d_in[12];
    float* out = (float*)d_out;

    const int* src = eidx;
    const int* dst = eidx + N_EDGES;

    char* p = (char*)d_ws;
    float* T    = (float*)p;   p += (size_t)N_NODES * F * sizeof(float);
    float* A    = (float*)p;   p += (size_t)N_NODES * F * sizeof(float);
    float* B    = (float*)p;   p += (size_t)N_NODES * F * sizeof(float);
    float* dinv = (float*)p;   p += (size_t)N_NODES * sizeof(float);
    int* cnt     = (int*)p;    p += (size_t)N_NODES * sizeof(int);
    int* row_ptr = (int*)p;    p += (size_t)(N_NODES + 1) * sizeof(int);
    int* blksums = (int*)p;    p += 256 * sizeof(int);
    int* esrc    = (int*)p;    p += (size_t)N_EDGES * sizeof(int);

    dim3 b256(256);
    int gNodes   = (N_NODES + 255) / 256;
    int gEdges   = (N_EDGES + 255) / 256;
    int gGemm    = (N_NODES + TM - 1) / TM;
    int gGather  = (N_NODES + NB - 1) / NB;

    // ---- CSR build ----
    hipMemsetAsync(cnt, 0, (size_t)N_NODES * sizeof(int), stream);
    k_hist<<<gEdges, b256, 0, stream>>>(dst, cnt, N_EDGES);
    k_scan1<<<gNodes, b256, 0, stream>>>(cnt, row_ptr, blksums, dinv, N_NODES);
    k_scan2<<<1, b256, 0, stream>>>(blksums, gNodes);
    k_scan3<<<gNodes, b256, 0, stream>>>(row_ptr, blksums, N_NODES, N_EDGES);
    k_fill<<<gEdges, b256, 0, stream>>>(src, dst, row_ptr, cnt, esrc, N_EDGES);

    // ---- layer 1: x -> A ----
    k_gemm128<<<gGemm, b256, 0, stream>>>(x, W1, T, N_NODES);
    k_gather<<<gGather, b256, 0, stream>>>(row_ptr, esrc, dinv, T, b1, A, N_NODES);

    // ---- layer 2: A -> B ----
    k_gemm128<<<gGemm, b256, 0, stream>>>(A, W2, T, N_NODES);
    k_gather<<<gGather, b256, 0, stream>>>(row_ptr, esrc, dinv, T, b2, B, N_NODES);

    // ---- layer 3: B -> A ----
    k_gemm128<<<gGemm, b256, 0, stream>>>(B, W3, T, N_NODES);
    k_gather<<<gGather, b256, 0, stream>>>(row_ptr, esrc, dinv, T, b3, A, N_NODES);

    // ---- pool + FC ----
    k_pool_fc<<<N_GRAPHS, b256, 0, stream>>>(A, batch, Wf1, bf1, Wf2, bf2, out);
}

// Round 6
// 371.521 us; speedup vs baseline: 4.8388x; 4.8388x over previous
//
#include <hip/hip_runtime.h>

#define N_NODES 50000
#define N_EDGES 600000
#define N_GRAPHS 500
#define F 128
#define F4 (F/4)

// ================= CSR build =================
__global__ __launch_bounds__(256) void k_hist(const int* __restrict__ dst, int* __restrict__ cnt, int ne) {
    int e = blockIdx.x * 256 + threadIdx.x;
    if (e < ne) atomicAdd(&cnt[dst[e]], 1);
}

__global__ __launch_bounds__(256) void k_scan1(const int* __restrict__ cnt, int* __restrict__ row_ptr,
                                               int* __restrict__ blksums, float* __restrict__ dinv, int n) {
    __shared__ int s[256];
    int i = blockIdx.x * 256 + threadIdx.x;
    int v = (i < n) ? cnt[i] : 0;
    if (i < n) dinv[i] = rsqrtf((float)(v + 1));   // self-loop included
    s[threadIdx.x] = v;
    __syncthreads();
    for (int off = 1; off < 256; off <<= 1) {
        int t = (threadIdx.x >= off) ? s[threadIdx.x - off] : 0;
        __syncthreads();
        s[threadIdx.x] += t;
        __syncthreads();
    }
    if (i < n) row_ptr[i] = s[threadIdx.x] - v;
    if (threadIdx.x == 255) blksums[blockIdx.x] = s[255];
}

__global__ __launch_bounds__(256) void k_scan2(int* __restrict__ blksums, int nb) {
    __shared__ int s[256];
    int v = (threadIdx.x < nb) ? blksums[threadIdx.x] : 0;
    s[threadIdx.x] = v;
    __syncthreads();
    for (int off = 1; off < 256; off <<= 1) {
        int t = (threadIdx.x >= off) ? s[threadIdx.x - off] : 0;
        __syncthreads();
        s[threadIdx.x] += t;
        __syncthreads();
    }
    if (threadIdx.x < nb) blksums[threadIdx.x] = s[threadIdx.x] - v;
}

__global__ __launch_bounds__(256) void k_scan3(int* __restrict__ row_ptr, const int* __restrict__ blksums,
                                               int n, int ne) {
    int i = blockIdx.x * 256 + threadIdx.x;
    if (i < n) row_ptr[i] += blksums[blockIdx.x];
    if (i == 0) row_ptr[n] = ne;
}

// count-down fill: cnt holds degrees on entry (consumed here)
__global__ __launch_bounds__(256) void k_fill(const int* __restrict__ src, const int* __restrict__ dst,
                                              const int* __restrict__ row_ptr, int* __restrict__ cnt,
                                              int* __restrict__ esrc, int ne) {
    int e = blockIdx.x * 256 + threadIdx.x;
    if (e < ne) {
        int d = dst[e];
        int pos = row_ptr[d] + atomicSub(&cnt[d], 1) - 1;
        esrc[pos] = src[e];
    }
}

// ---- fp32 -> bf16 RNE pack ----
__device__ inline unsigned pk_bf16(float a, float b) {
    unsigned ua = __float_as_uint(a), ub = __float_as_uint(b);
    ua = (ua + 0x7fffu + ((ua >> 16) & 1u)) >> 16;
    ub = (ub + 0x7fffu + ((ub >> 16) & 1u)) >> 16;
    return ua | (ub << 16);
}
#define BF_LO(u) __uint_as_float((u) << 16)
#define BF_HI(u) __uint_as_float((u) & 0xffff0000u)

// ================= GEMM: Tb = bf16(X @ W)  (X:[n,128] fp32, W:[128,128]) ===========
#define TM 64
#define FMA4(A, S, Wv) { A.x = fmaf(S, Wv.x, A.x); A.y = fmaf(S, Wv.y, A.y); \
                         A.z = fmaf(S, Wv.z, A.z); A.w = fmaf(S, Wv.w, A.w); }

__global__ __launch_bounds__(256) void k_gemm128(const float* __restrict__ X,
                                                 const float* __restrict__ W,
                                                 unsigned short* __restrict__ Tb, int n_rows) {
    __shared__ float Xs[32 * TM];   // [kk][row]
    __shared__ float Ws[32 * F];    // [kk][col]
    int tid  = threadIdx.x;
    int row0 = blockIdx.x * TM;
    int cg = tid & 15;
    int rg = tid >> 4;
    int j0 = cg * 4;
    int r0 = rg * 4;
    int srow = tid >> 2;
    int skb  = (tid & 3) * 8;
    bool rvalid = (row0 + srow) < n_rows;
    const float* Xrow = X + (size_t)(row0 + srow) * F;

    float4 accA[4], accB[4];
    #pragma unroll
    for (int i = 0; i < 4; i++) { accA[i] = make_float4(0,0,0,0); accB[i] = make_float4(0,0,0,0); }

    for (int kc = 0; kc < 4; ++kc) {
        __syncthreads();
        #pragma unroll
        for (int q = 0; q < 4; ++q) {
            int i = tid + 256 * q;
            ((float4*)Ws)[i] = ((const float4*)(W + (size_t)kc * 32 * F))[i];
        }
        float4 xv0 = make_float4(0,0,0,0), xv1 = make_float4(0,0,0,0);
        if (rvalid) {
            xv0 = ((const float4*)(Xrow + kc * 32 + skb))[0];
            xv1 = ((const float4*)(Xrow + kc * 32 + skb))[1];
        }
        Xs[(skb + 0) * TM + srow] = xv0.x;
        Xs[(skb + 1) * TM + srow] = xv0.y;
        Xs[(skb + 2) * TM + srow] = xv0.z;
        Xs[(skb + 3) * TM + srow] = xv0.w;
        Xs[(skb + 4) * TM + srow] = xv1.x;
        Xs[(skb + 5) * TM + srow] = xv1.y;
        Xs[(skb + 6) * TM + srow] = xv1.z;
        Xs[(skb + 7) * TM + srow] = xv1.w;
        __syncthreads();
        #pragma unroll
        for (int kk = 0; kk < 32; ++kk) {
            float4 xa = *(const float4*)&Xs[kk * TM + r0];
            float4 wa = *(const float4*)&Ws[kk * F + j0];
            float4 wb = *(const float4*)&Ws[kk * F + j0 + 64];
            FMA4(accA[0], xa.x, wa); FMA4(accB[0], xa.x, wb);
            FMA4(accA[1], xa.y, wa); FMA4(accB[1], xa.y, wb);
            FMA4(accA[2], xa.z, wa); FMA4(accB[2], xa.z, wb);
            FMA4(accA[3], xa.w, wa); FMA4(accB[3], xa.w, wb);
        }
    }
    #pragma unroll
    for (int i = 0; i < 4; ++i) {
        int row = row0 + r0 + i;
        if (row < n_rows) {
            unsigned short* Trow = Tb + (size_t)row * F;
            uint2 va, vb;
            va.x = pk_bf16(accA[i].x, accA[i].y);
            va.y = pk_bf16(accA[i].z, accA[i].w);
            vb.x = pk_bf16(accB[i].x, accB[i].y);
            vb.y = pk_bf16(accB[i].z, accB[i].w);
            ((uint2*)Trow)[cg]      = va;
            ((uint2*)Trow)[cg + 16] = vb;
        }
    }
}

// ============ fused gather + self-loop + bias + ReLU (bf16 T rows) ============
// one wave per node; 4 quarter-waves (16 lanes) process 4 edges/iter;
// each lane loads one uint4 = 8 bf16 feats. Depth-3 pipeline (2 rows in flight).
// Self-loop = virtual edge at `end` with weight dd^2.
__global__ __launch_bounds__(256) void k_gather(const int* __restrict__ row_ptr,
                                                const int* __restrict__ esrc,
                                                const float* __restrict__ dinv,
                                                const unsigned short* __restrict__ Tb,
                                                const float* __restrict__ bias,
                                                float* __restrict__ H, int n) {
    int node = blockIdx.x * 4 + (threadIdx.x >> 6);
    if (node >= n) return;
    int lane = threadIdx.x & 63;
    int q    = lane >> 4;
    int sub  = lane & 15;
    int beg = row_ptr[node], end = row_ptr[node + 1];
    float dd = dinv[node];

    int m = end - beg + 1;          // incl. virtual self edge
    int iters = (m + 3) >> 2;

    int e = beg + q;
    int s0; float w0;
    if (e < end)       { s0 = esrc[e]; w0 = dinv[s0] * dd; }
    else if (e == end) { s0 = node;    w0 = dd * dd; }
    else               { s0 = node;    w0 = 0.f; }
    uint4 u0 = ((const uint4*)(Tb + (size_t)s0 * F))[sub];

    int e1 = e + 4;
    int s1; float w1;
    if (e1 < end)       { s1 = esrc[e1]; w1 = dinv[s1] * dd; }
    else if (e1 == end) { s1 = node;     w1 = dd * dd; }
    else                { s1 = node;     w1 = 0.f; }
    uint4 u1 = ((const uint4*)(Tb + (size_t)s1 * F))[sub];

    int e2 = e + 8;
    int s2; float w2;
    if (e2 < end)       { s2 = esrc[e2]; w2 = dinv[s2] * dd; }
    else if (e2 == end) { s2 = node;     w2 = dd * dd; }
    else                { s2 = node;     w2 = 0.f; }

    float4 accL = make_float4(0,0,0,0), accH = make_float4(0,0,0,0);
    for (int it = 2; it < iters; ++it) {
        uint4 u2 = ((const uint4*)(Tb + (size_t)s2 * F))[sub];
        int e3 = e + 4 * (it + 1);
        int s3; float w3;
        if (e3 < end)       { s3 = esrc[e3]; w3 = dinv[s3] * dd; }
        else if (e3 == end) { s3 = node;     w3 = dd * dd; }
        else                { s3 = node;     w3 = 0.f; }
        accL.x = fmaf(BF_LO(u0.x), w0, accL.x);
        accL.y = fmaf(BF_HI(u0.x), w0, accL.y);
        accL.z = fmaf(BF_LO(u0.y), w0, accL.z);
        accL.w = fmaf(BF_HI(u0.y), w0, accL.w);
        accH.x = fmaf(BF_LO(u0.z), w0, accH.x);
        accH.y = fmaf(BF_HI(u0.z), w0, accH.y);
        accH.z = fmaf(BF_LO(u0.w), w0, accH.z);
        accH.w = fmaf(BF_HI(u0.w), w0, accH.w);
        u0 = u1; w0 = w1;
        u1 = u2; w1 = w2;
        s2 = s3; w2 = w3;
    }
    accL.x = fmaf(BF_LO(u0.x), w0, accL.x);
    accL.y = fmaf(BF_HI(u0.x), w0, accL.y);
    accL.z = fmaf(BF_LO(u0.y), w0, accL.z);
    accL.w = fmaf(BF_HI(u0.y), w0, accL.w);
    accH.x = fmaf(BF_LO(u0.z), w0, accH.x);
    accH.y = fmaf(BF_HI(u0.z), w0, accH.y);
    accH.z = fmaf(BF_LO(u0.w), w0, accH.z);
    accH.w = fmaf(BF_HI(u0.w), w0, accH.w);
    accL.x = fmaf(BF_LO(u1.x), w1, accL.x);
    accL.y = fmaf(BF_HI(u1.x), w1, accL.y);
    accL.z = fmaf(BF_LO(u1.y), w1, accL.z);
    accL.w = fmaf(BF_HI(u1.y), w1, accL.w);
    accH.x = fmaf(BF_LO(u1.z), w1, accH.x);
    accH.y = fmaf(BF_HI(u1.z), w1, accH.y);
    accH.z = fmaf(BF_LO(u1.w), w1, accH.z);
    accH.w = fmaf(BF_HI(u1.w), w1, accH.w);

    // combine quarter-wave partials: lane^16 then lane^32
    accL.x += __shfl_xor(accL.x, 16, 64); accH.x += __shfl_xor(accH.x, 16, 64);
    accL.y += __shfl_xor(accL.y, 16, 64); accH.y += __shfl_xor(accH.y, 16, 64);
    accL.z += __shfl_xor(accL.z, 16, 64); accH.z += __shfl_xor(accH.z, 16, 64);
    accL.w += __shfl_xor(accL.w, 16, 64); accH.w += __shfl_xor(accH.w, 16, 64);
    accL.x += __shfl_xor(accL.x, 32, 64); accH.x += __shfl_xor(accH.x, 32, 64);
    accL.y += __shfl_xor(accL.y, 32, 64); accH.y += __shfl_xor(accH.y, 32, 64);
    accL.z += __shfl_xor(accL.z, 32, 64); accH.z += __shfl_xor(accH.z, 32, 64);
    accL.w += __shfl_xor(accL.w, 32, 64); accH.w += __shfl_xor(accH.w, 32, 64);

    if (lane < 16) {
        // lane holds feats sub*8 .. sub*8+7
        const float4* bb = (const float4*)(bias + sub * 8);
        float4 b0 = bb[0], b1v = bb[1];
        float4 r0, r1;
        r0.x = fmaxf(accL.x + b0.x, 0.f);
        r0.y = fmaxf(accL.y + b0.y, 0.f);
        r0.z = fmaxf(accL.z + b0.z, 0.f);
        r0.w = fmaxf(accL.w + b0.w, 0.f);
        r1.x = fmaxf(accH.x + b1v.x, 0.f);
        r1.y = fmaxf(accH.y + b1v.y, 0.f);
        r1.z = fmaxf(accH.z + b1v.z, 0.f);
        r1.w = fmaxf(accH.w + b1v.w, 0.f);
        float4* op = (float4*)(H + (size_t)node * F + sub * 8);
        op[0] = r0;
        op[1] = r1;
    }
}

// ============ fused pool (segment mean) + FC head ============
__global__ __launch_bounds__(256) void k_pool_fc(const float* __restrict__ H,
                                                 const int* __restrict__ batch,
                                                 const float* __restrict__ Wf1,
                                                 const float* __restrict__ bf1,
                                                 const float* __restrict__ Wf2,
                                                 const float* __restrict__ bf2,
                                                 float* __restrict__ out) {
    int g = blockIdx.x;
    int tid = threadIdx.x;
    int lo = 0, hi = N_NODES;
    while (lo < hi) { int mid = (lo + hi) >> 1; if (batch[mid] < g) lo = mid + 1; else hi = mid; }
    int start = lo;
    hi = N_NODES;
    while (lo < hi) { int mid = (lo + hi) >> 1; if (batch[mid] <= g) lo = mid + 1; else hi = mid; }
    int end = lo;

    __shared__ float hs[4][F];
    __shared__ float hg[F];
    int wv = tid >> 6, lane = tid & 63;
    int half = lane >> 5, sub = lane & 31;
    float4 a = make_float4(0.f, 0.f, 0.f, 0.f);
    for (int i = start + wv * 2 + half; i < end; i += 8) {
        float4 v = ((const float4*)(H + (size_t)i * F))[sub];
        a.x += v.x; a.y += v.y; a.z += v.z; a.w += v.w;
    }
    a.x += __shfl_xor(a.x, 32, 64);
    a.y += __shfl_xor(a.y, 32, 64);
    a.z += __shfl_xor(a.z, 32, 64);
    a.w += __shfl_xor(a.w, 32, 64);
    if (half == 0) ((float4*)hs[wv])[sub] = a;
    __syncthreads();
    if (tid < F) {
        float inv = 1.0f / (float)((end - start) > 0 ? (end - start) : 1);
        hg[tid] = (hs[0][tid] + hs[1][tid] + hs[2][tid] + hs[3][tid]) * inv;
    }
    __syncthreads();
    if (tid < 64) {
        float acc = bf1[tid];
        #pragma unroll 4
        for (int f = 0; f < F; ++f) acc = fmaf(hg[f], Wf1[f * 64 + tid], acc);
        float v = fmaxf(acc, 0.f) * Wf2[tid];
        #pragma unroll
        for (int off = 32; off > 0; off >>= 1) v += __shfl_down(v, off, 64);
        if (tid == 0) out[g] = v + bf2[0];
    }
}

extern "C" void kernel_launch(void* const* d_in, const int* in_sizes, int n_in,
                              void* d_out, int out_size, void* d_ws, size_t ws_size,
                              hipStream_t stream) {
    const float* x    = (const float*)d_in[0];
    const int* eidx   = (const int*)d_in[1];
    const int* batch  = (const int*)d_in[2];
    const float* W1   = (const float*)d_in[3];
    const float* b1   = (const float*)d_in[4];
    const float* W2   = (const float*)d_in[5];
    const float* b2   = (const float*)d_in[6];
    const float* W3   = (const float*)d_in[7];
    const float* b3   = (const float*)d_in[8];
    const float* Wf1  = (const float*)d_in[9];
    const float* bf1  = (const float*)d_in[10];
    const float* Wf2  = (const float*)d_in[11];
    const float* bf2  = (const float*)d_in[12];
    float* out = (float*)d_out;

    const int* src = eidx;
    const int* dst = eidx + N_EDGES;

    char* p = (char*)d_ws;
    unsigned short* Tb = (unsigned short*)p;  p += (size_t)N_NODES * F * sizeof(unsigned short);
    float* A    = (float*)p;   p += (size_t)N_NODES * F * sizeof(float);
    float* B    = (float*)p;   p += (size_t)N_NODES * F * sizeof(float);
    float* dinv = (float*)p;   p += (size_t)N_NODES * sizeof(float);
    int* cnt     = (int*)p;    p += (size_t)N_NODES * sizeof(int);
    int* row_ptr = (int*)p;    p += (size_t)(N_NODES + 1) * sizeof(int);
    int* blksums = (int*)p;    p += 256 * sizeof(int);
    int* esrc    = (int*)p;    p += (size_t)N_EDGES * sizeof(int);

    dim3 b256(256);
    int gNodes   = (N_NODES + 255) / 256;
    int gEdges   = (N_EDGES + 255) / 256;
    int gGemm    = (N_NODES + TM - 1) / TM;
    int gGather  = (N_NODES + 3) / 4;

    // ---- CSR build ----
    hipMemsetAsync(cnt, 0, (size_t)N_NODES * sizeof(int), stream);
    k_hist<<<gEdges, b256, 0, stream>>>(dst, cnt, N_EDGES);
    k_scan1<<<gNodes, b256, 0, stream>>>(cnt, row_ptr, blksums, dinv, N_NODES);
    k_scan2<<<1, b256, 0, stream>>>(blksums, gNodes);
    k_scan3<<<gNodes, b256, 0, stream>>>(row_ptr, blksums, N_NODES, N_EDGES);
    k_fill<<<gEdges, b256, 0, stream>>>(src, dst, row_ptr, cnt, esrc, N_EDGES);

    // ---- layer 1: x -> A ----
    k_gemm128<<<gGemm, b256, 0, stream>>>(x, W1, Tb, N_NODES);
    k_gather<<<gGather, b256, 0, stream>>>(row_ptr, esrc, dinv, Tb, b1, A, N_NODES);

    // ---- layer 2: A -> B ----
    k_gemm128<<<gGemm, b256, 0, stream>>>(A, W2, Tb, N_NODES);
    k_gather<<<gGather, b256, 0, stream>>>(row_ptr, esrc, dinv, Tb, b2, B, N_NODES);

    // ---- layer 3: B -> A ----
    k_gemm128<<<gGemm, b256, 0, stream>>>(B, W3, Tb, N_NODES);
    k_gather<<<gGather, b256, 0, stream>>>(row_ptr, esrc, dinv, Tb, b3, A, N_NODES);

    // ---- pool + FC ----
    k_pool_fc<<<N_GRAPHS, b256, 0, stream>>>(A, batch, Wf1, bf1, Wf2, bf2, out);
}

// Round 8
// 301.261 us; speedup vs baseline: 5.9673x; 1.2332x over previous
//
#include <hip/hip_runtime.h>

#define N_NODES 50000
#define N_EDGES 600000
#define N_GRAPHS 500
#define F 128

typedef short bf16x8 __attribute__((ext_vector_type(8)));
typedef float f32x4 __attribute__((ext_vector_type(4)));
union U4H8 { uint4 u; bf16x8 h; };

// ---- bf16 helpers (RNE) ----
__device__ inline unsigned pk_bf16(float a, float b) {
    unsigned ua = __float_as_uint(a), ub = __float_as_uint(b);
    ua = (ua + 0x7fffu + ((ua >> 16) & 1u)) >> 16;
    ub = (ub + 0x7fffu + ((ub >> 16) & 1u)) >> 16;
    return ua | (ub << 16);
}
__device__ inline float bf16_rnd(float x) {      // round to bf16, keep as fp32
    unsigned u = __float_as_uint(x);
    u = (u + 0x7fffu + ((u >> 16) & 1u)) & 0xffff0000u;
    return __uint_as_float(u);
}
__device__ inline unsigned short bf16_1(float a) {
    unsigned ua = __float_as_uint(a);
    return (unsigned short)((ua + 0x7fffu + ((ua >> 16) & 1u)) >> 16);
}
#define BF_LO(u) __uint_as_float((u) << 16)
#define BF_HI(u) __uint_as_float((u) & 0xffff0000u)

// ================= CSR build =================
__global__ __launch_bounds__(256) void k_hist(const int* __restrict__ dst, int* __restrict__ cnt, int ne) {
    int e = blockIdx.x * 256 + threadIdx.x;
    if (e < ne) atomicAdd(&cnt[dst[e]], 1);
}

__global__ __launch_bounds__(256) void k_scan1(const int* __restrict__ cnt, int* __restrict__ row_ptr,
                                               int* __restrict__ blksums, float* __restrict__ dinv, int n) {
    __shared__ int s[256];
    int i = blockIdx.x * 256 + threadIdx.x;
    int v = (i < n) ? cnt[i] : 0;
    if (i < n) dinv[i] = rsqrtf((float)(v + 1));   // self-loop included
    s[threadIdx.x] = v;
    __syncthreads();
    for (int off = 1; off < 256; off <<= 1) {
        int t = (threadIdx.x >= off) ? s[threadIdx.x - off] : 0;
        __syncthreads();
        s[threadIdx.x] += t;
        __syncthreads();
    }
    if (i < n) row_ptr[i] = s[threadIdx.x] - v;
    if (threadIdx.x == 255) blksums[blockIdx.x] = s[255];
}

__global__ __launch_bounds__(256) void k_scan2(int* __restrict__ blksums, int nb) {
    __shared__ int s[256];
    int v = (threadIdx.x < nb) ? blksums[threadIdx.x] : 0;
    s[threadIdx.x] = v;
    __syncthreads();
    for (int off = 1; off < 256; off <<= 1) {
        int t = (threadIdx.x >= off) ? s[threadIdx.x - off] : 0;
        __syncthreads();
        s[threadIdx.x] += t;
        __syncthreads();
    }
    if (threadIdx.x < nb) blksums[threadIdx.x] = s[threadIdx.x] - v;
}

__global__ __launch_bounds__(256) void k_scan3(int* __restrict__ row_ptr, const int* __restrict__ blksums,
                                               int n, int ne) {
    int i = blockIdx.x * 256 + threadIdx.x;
    if (i < n) row_ptr[i] += blksums[blockIdx.x];
    if (i == 0) row_ptr[n] = ne;
}

// count-down fill; stores {src, dinv[src]} per CSR slot
__global__ __launch_bounds__(256) void k_fill(const int* __restrict__ src, const int* __restrict__ dst,
                                              const int* __restrict__ row_ptr, int* __restrict__ cnt,
                                              const float* __restrict__ dinv,
                                              int2* __restrict__ esw, int ne) {
    int e = blockIdx.x * 256 + threadIdx.x;
    if (e < ne) {
        int d = dst[e];
        int s = src[e];
        int pos = row_ptr[d] + atomicSub(&cnt[d], 1) - 1;
        esw[pos] = make_int2(s, __float_as_int(dinv[s]));
    }
}

// ================= W pre-pack: split bf16 hi/lo, B-fragment order, 3 layers =================
// frag index: [(s*8+c)*64 + lane] -> 8 bf16 of W[32s+8q+j][16c+m], q=lane>>4, m=lane&15
__global__ __launch_bounds__(256) void k_prepW(const float* __restrict__ W1, const float* __restrict__ W2,
                                               const float* __restrict__ W3,
                                               uint4* __restrict__ Whi, uint4* __restrict__ Wlo) {
    int idx = blockIdx.x * 256 + threadIdx.x;   // 0..6143
    int layer = idx >> 11;
    const float* W = (layer == 0) ? W1 : (layer == 1) ? W2 : W3;
    int t = idx & 2047;
    int lane = t & 63, sc = t >> 6;
    int s = sc >> 3, c = sc & 7;
    int q = lane >> 4, m = lane & 15;
    int k0 = 32 * s + 8 * q, n0 = 16 * c + m;
    float w[8], h[8];
    #pragma unroll
    for (int j = 0; j < 8; ++j) {
        w[j] = W[(k0 + j) * F + n0];
        h[j] = bf16_rnd(w[j]);
    }
    uint4 uh, ul;
    uh.x = pk_bf16(h[0], h[1]); uh.y = pk_bf16(h[2], h[3]);
    uh.z = pk_bf16(h[4], h[5]); uh.w = pk_bf16(h[6], h[7]);
    ul.x = pk_bf16(w[0] - h[0], w[1] - h[1]); ul.y = pk_bf16(w[2] - h[2], w[3] - h[3]);
    ul.z = pk_bf16(w[4] - h[4], w[5] - h[5]); ul.w = pk_bf16(w[6] - h[6], w[7] - h[7]);
    Whi[idx] = uh;
    Wlo[idx] = ul;
}

// ================= split-bf16 MFMA GEMM: Tb = bf16(X(fp32) @ W) =================
// 64 rows/block, 4 waves; wave owns rows [16w,16w+16). 8 col-tiles, 4 k-steps, 3 MFMAs each.
__global__ __launch_bounds__(256) void k_gemm_mfma(const float* __restrict__ X,
                                                   const uint4* __restrict__ Whi,
                                                   const uint4* __restrict__ Wlo,
                                                   unsigned short* __restrict__ Tb, int n_rows) {
    __shared__ uint4 Wl[4096];   // hi[0..2047], lo[2048..4095] : 64 KB
    int tid = threadIdx.x;
    #pragma unroll
    for (int i = 0; i < 8; ++i) {
        Wl[tid + 256 * i] = Whi[tid + 256 * i];
        Wl[2048 + tid + 256 * i] = Wlo[tid + 256 * i];
    }
    __syncthreads();
    int wave = tid >> 6, lane = tid & 63;
    int q = lane >> 4, m = lane & 15;
    int rowA = blockIdx.x * 64 + wave * 16 + m;
    int rowAc = rowA < n_rows ? rowA : (n_rows - 1);
    f32x4 acc[8];
    #pragma unroll
    for (int c = 0; c < 8; ++c) acc[c] = (f32x4){0.f, 0.f, 0.f, 0.f};
    #pragma unroll
    for (int s = 0; s < 4; ++s) {
        const float* xr = X + (size_t)rowAc * F + 32 * s + 8 * q;
        float4 f0 = ((const float4*)xr)[0];
        float4 f1 = ((const float4*)xr)[1];
        float h0 = bf16_rnd(f0.x), h1 = bf16_rnd(f0.y), h2 = bf16_rnd(f0.z), h3 = bf16_rnd(f0.w);
        float h4 = bf16_rnd(f1.x), h5 = bf16_rnd(f1.y), h6 = bf16_rnd(f1.z), h7 = bf16_rnd(f1.w);
        U4H8 ahi, alo;
        ahi.u.x = (__float_as_uint(h0) >> 16) | (__float_as_uint(h1) & 0xffff0000u);
        ahi.u.y = (__float_as_uint(h2) >> 16) | (__float_as_uint(h3) & 0xffff0000u);
        ahi.u.z = (__float_as_uint(h4) >> 16) | (__float_as_uint(h5) & 0xffff0000u);
        ahi.u.w = (__float_as_uint(h6) >> 16) | (__float_as_uint(h7) & 0xffff0000u);
        alo.u.x = pk_bf16(f0.x - h0, f0.y - h1);
        alo.u.y = pk_bf16(f0.z - h2, f0.w - h3);
        alo.u.z = pk_bf16(f1.x - h4, f1.y - h5);
        alo.u.w = pk_bf16(f1.z - h6, f1.w - h7);
        #pragma unroll
        for (int c = 0; c < 8; ++c) {
            U4H8 bh, bl;
            bh.u = Wl[(s * 8 + c) * 64 + lane];
            bl.u = Wl[2048 + (s * 8 + c) * 64 + lane];
            acc[c] = __builtin_amdgcn_mfma_f32_16x16x32_bf16(ahi.h, bh.h, acc[c], 0, 0, 0);
            acc[c] = __builtin_amdgcn_mfma_f32_16x16x32_bf16(alo.h, bh.h, acc[c], 0, 0, 0);
            acc[c] = __builtin_amdgcn_mfma_f32_16x16x32_bf16(ahi.h, bl.h, acc[c], 0, 0, 0);
        }
    }
    // C/D layout: col = lane&15, row = (lane>>4)*4 + reg
    int outr0 = blockIdx.x * 64 + wave * 16 + 4 * q;
    #pragma unroll
    for (int c = 0; c < 8; ++c) {
        #pragma unroll
        for (int r = 0; r < 4; ++r) {
            int rr = outr0 + r;
            if (rr < n_rows) Tb[(size_t)rr * F + 16 * c + m] = bf16_1(acc[c][r]);
        }
    }
}

// ============ gather: 16-lane group per node, flat 16-deep pipeline ============
// Group loads 16 edge records in parallel (one int2/lane), shfl-broadcasts,
// issues all 16 row loads, then consumes. Self-loop = virtual edge at `end`.
// Accumulates fp32, writes fp32 H (+bias, ReLU fused).
__global__ __launch_bounds__(256) void k_gather(const int* __restrict__ row_ptr,
                                                const int2* __restrict__ esw,
                                                const float* __restrict__ dinv,
                                                const unsigned short* __restrict__ Tb,
                                                const float* __restrict__ bias,
                                                float* __restrict__ H, int n) {
    int grp = threadIdx.x >> 4;
    int node = blockIdx.x * 16 + grp;
    if (node >= n) return;
    int sub = threadIdx.x & 15;
    int beg = row_ptr[node], end = row_ptr[node + 1];
    float dd = dinv[node];

    float4 accL = make_float4(0.f, 0.f, 0.f, 0.f);
    float4 accH = make_float4(0.f, 0.f, 0.f, 0.f);

    for (int chunk = beg; chunk <= end; chunk += 16) {
        int e = chunk + sub;
        int2 rec;
        if (e < end)       rec = esw[e];
        else if (e == end) rec = make_int2(node, __float_as_int(dd));
        else               rec = make_int2(node, 0);

        uint4 rows[16];
        #pragma unroll
        for (int j = 0; j < 16; ++j) {
            int sj = __shfl(rec.x, j, 16);
            rows[j] = ((const uint4*)(Tb + (size_t)sj * F))[sub];
        }
        #pragma unroll
        for (int j = 0; j < 16; ++j) {
            float wj = __uint_as_float((unsigned)__shfl(rec.y, j, 16)) * dd;
            accL.x = fmaf(BF_LO(rows[j].x), wj, accL.x);
            accL.y = fmaf(BF_HI(rows[j].x), wj, accL.y);
            accL.z = fmaf(BF_LO(rows[j].y), wj, accL.z);
            accL.w = fmaf(BF_HI(rows[j].y), wj, accL.w);
            accH.x = fmaf(BF_LO(rows[j].z), wj, accH.x);
            accH.y = fmaf(BF_HI(rows[j].z), wj, accH.y);
            accH.z = fmaf(BF_LO(rows[j].w), wj, accH.z);
            accH.w = fmaf(BF_HI(rows[j].w), wj, accH.w);
        }
    }

    const float4* bb = (const float4*)(bias + sub * 8);
    float4 b0 = bb[0], b1 = bb[1];
    float4 r0, r1;
    r0.x = fmaxf(accL.x + b0.x, 0.f);
    r0.y = fmaxf(accL.y + b0.y, 0.f);
    r0.z = fmaxf(accL.z + b0.z, 0.f);
    r0.w = fmaxf(accL.w + b0.w, 0.f);
    r1.x = fmaxf(accH.x + b1.x, 0.f);
    r1.y = fmaxf(accH.y + b1.y, 0.f);
    r1.z = fmaxf(accH.z + b1.z, 0.f);
    r1.w = fmaxf(accH.w + b1.w, 0.f);
    float4* op = (float4*)(H + (size_t)node * F + sub * 8);
    op[0] = r0;
    op[1] = r1;
}

// ============ fused pool (segment mean) + FC head ============
__global__ __launch_bounds__(256) void k_pool_fc(const float* __restrict__ H,
                                                 const int* __restrict__ batch,
                                                 const float* __restrict__ Wf1,
                                                 const float* __restrict__ bf1,
                                                 const float* __restrict__ Wf2,
                                                 const float* __restrict__ bf2,
                                                 float* __restrict__ out) {
    int g = blockIdx.x;
    int tid = threadIdx.x;
    int lo = 0, hi = N_NODES;
    while (lo < hi) { int mid = (lo + hi) >> 1; if (batch[mid] < g) lo = mid + 1; else hi = mid; }
    int start = lo;
    hi = N_NODES;
    while (lo < hi) { int mid = (lo + hi) >> 1; if (batch[mid] <= g) lo = mid + 1; else hi = mid; }
    int end = lo;

    __shared__ float hs[4][F];
    __shared__ float hg[F];
    int wv = tid >> 6, lane = tid & 63;
    int half = lane >> 5, sub = lane & 31;
    float4 a = make_float4(0.f, 0.f, 0.f, 0.f);
    for (int i = start + wv * 2 + half; i < end; i += 8) {
        float4 v = ((const float4*)(H + (size_t)i * F))[sub];
        a.x += v.x; a.y += v.y; a.z += v.z; a.w += v.w;
    }
    a.x += __shfl_xor(a.x, 32, 64);
    a.y += __shfl_xor(a.y, 32, 64);
    a.z += __shfl_xor(a.z, 32, 64);
    a.w += __shfl_xor(a.w, 32, 64);
    if (half == 0) ((float4*)hs[wv])[sub] = a;
    __syncthreads();
    if (tid < F) {
        float inv = 1.0f / (float)((end - start) > 0 ? (end - start) : 1);
        hg[tid] = (hs[0][tid] + hs[1][tid] + hs[2][tid] + hs[3][tid]) * inv;
    }
    __syncthreads();
    if (tid < 64) {
        float acc = bf1[tid];
        #pragma unroll 4
        for (int f = 0; f < F; ++f) acc = fmaf(hg[f], Wf1[f * 64 + tid], acc);
        float v = fmaxf(acc, 0.f) * Wf2[tid];
        #pragma unroll
        for (int off = 32; off > 0; off >>= 1) v += __shfl_down(v, off, 64);
        if (tid == 0) out[g] = v + bf2[0];
    }
}

extern "C" void kernel_launch(void* const* d_in, const int* in_sizes, int n_in,
                              void* d_out, int out_size, void* d_ws, size_t ws_size,
                              hipStream_t stream) {
    const float* x    = (const float*)d_in[0];
    const int* eidx   = (const int*)d_in[1];
    const int* batch  = (const int*)d_in[2];
    const float* W1   = (const float*)d_in[3];
    const float* b1   = (const float*)d_in[4];
    const float* W2   = (const float*)d_in[5];
    const float* b2   = (const float*)d_in[6];
    const float* W3   = (const float*)d_in[7];
    const float* b3   = (const float*)d_in[8];
    const float* Wf1  = (const float*)d_in[9];
    const float* bf1  = (const float*)d_in[10];
    const float* Wf2  = (const float*)d_in[11];
    const float* bf2  = (const float*)d_in[12];
    float* out = (float*)d_out;

    const int* src = eidx;
    const int* dst = eidx + N_EDGES;

    char* p = (char*)d_ws;
    unsigned short* Tb = (unsigned short*)p;  p += (size_t)N_NODES * F * 2;   // 12.8 MB
    float* Ha   = (float*)p;   p += (size_t)N_NODES * F * sizeof(float);      // 25.6 MB
    float* Hc   = (float*)p;   p += (size_t)N_NODES * F * sizeof(float);      // 25.6 MB
    int2* esw   = (int2*)p;    p += (size_t)N_EDGES * sizeof(int2);           // 4.8 MB
    uint4* Whi  = (uint4*)p;   p += (size_t)3 * 2048 * sizeof(uint4);
    uint4* Wlo  = (uint4*)p;   p += (size_t)3 * 2048 * sizeof(uint4);
    float* dinv = (float*)p;   p += (size_t)N_NODES * sizeof(float);
    int* cnt     = (int*)p;    p += (size_t)N_NODES * sizeof(int);
    int* row_ptr = (int*)p;    p += (size_t)(N_NODES + 1) * sizeof(int);
    int* blksums = (int*)p;    p += 256 * sizeof(int);

    dim3 b256(256);
    int gNodes   = (N_NODES + 255) / 256;
    int gEdges   = (N_EDGES + 255) / 256;
    int gGemm    = (N_NODES + 63) / 64;
    int gGather  = (N_NODES + 15) / 16;

    // ---- W pre-pack (independent of CSR) ----
    k_prepW<<<24, b256, 0, stream>>>(W1, W2, W3, Whi, Wlo);

    // ---- CSR build ----
    hipMemsetAsync(cnt, 0, (size_t)N_NODES * sizeof(int), stream);
    k_hist<<<gEdges, b256, 0, stream>>>(dst, cnt, N_EDGES);
    k_scan1<<<gNodes, b256, 0, stream>>>(cnt, row_ptr, blksums, dinv, N_NODES);
    k_scan2<<<1, b256, 0, stream>>>(blksums, gNodes);
    k_scan3<<<gNodes, b256, 0, stream>>>(row_ptr, blksums, N_NODES, N_EDGES);
    k_fill<<<gEdges, b256, 0, stream>>>(src, dst, row_ptr, cnt, dinv, esw, N_EDGES);

    // ---- layer 1: x -> Ha ----
    k_gemm_mfma<<<gGemm, b256, 0, stream>>>(x, Whi, Wlo, Tb, N_NODES);
    k_gather<<<gGather, b256, 0, stream>>>(row_ptr, esw, dinv, Tb, b1, Ha, N_NODES);

    // ---- layer 2: Ha -> Hc ----
    k_gemm_mfma<<<gGemm, b256, 0, stream>>>(Ha, Whi + 2048, Wlo + 2048, Tb, N_NODES);
    k_gather<<<gGather, b256, 0, stream>>>(row_ptr, esw, dinv, Tb, b2, Hc, N_NODES);

    // ---- layer 3: Hc -> Ha ----
    k_gemm_mfma<<<gGemm, b256, 0, stream>>>(Hc, Whi + 4096, Wlo + 4096, Tb, N_NODES);
    k_gather<<<gGather, b256, 0, stream>>>(row_ptr, esw, dinv, Tb, b3, Ha, N_NODES);

    // ---- pool + FC ----
    k_pool_fc<<<N_GRAPHS, b256, 0, stream>>>(Ha, batch, Wf1, bf1, Wf2, bf2, out);
}

// Round 9
// 296.095 us; speedup vs baseline: 6.0714x; 1.0174x over previous
//
#include <hip/hip_runtime.h>

#define N_NODES 50000
#define N_EDGES 600000
#define N_GRAPHS 500
#define F 128

typedef short bf16x8 __attribute__((ext_vector_type(8)));
typedef float f32x4 __attribute__((ext_vector_type(4)));
union U4H8 { uint4 u; bf16x8 h; };

// ---- bf16 helpers (RNE) ----
__device__ inline unsigned pk_bf16(float a, float b) {
    unsigned ua = __float_as_uint(a), ub = __float_as_uint(b);
    ua = (ua + 0x7fffu + ((ua >> 16) & 1u)) >> 16;
    ub = (ub + 0x7fffu + ((ub >> 16) & 1u)) >> 16;
    return ua | (ub << 16);
}
__device__ inline float bf16_rnd(float x) {
    unsigned u = __float_as_uint(x);
    u = (u + 0x7fffu + ((u >> 16) & 1u)) & 0xffff0000u;
    return __uint_as_float(u);
}
__device__ inline unsigned short bf16_1(float a) {
    unsigned ua = __float_as_uint(a);
    return (unsigned short)((ua + 0x7fffu + ((ua >> 16) & 1u)) >> 16);
}
#define BF_LO(u) __uint_as_float((u) << 16)
#define BF_HI(u) __uint_as_float((u) & 0xffff0000u)

// ================= CSR build =================
__global__ __launch_bounds__(256) void k_hist(const int* __restrict__ dst, int* __restrict__ cnt, int ne) {
    int e = blockIdx.x * 256 + threadIdx.x;
    if (e < ne) atomicAdd(&cnt[dst[e]], 1);
}

__global__ __launch_bounds__(256) void k_scan1(const int* __restrict__ cnt, int* __restrict__ row_ptr,
                                               int* __restrict__ blksums, float* __restrict__ dinv, int n) {
    __shared__ int s[256];
    int i = blockIdx.x * 256 + threadIdx.x;
    int v = (i < n) ? cnt[i] : 0;
    if (i < n) dinv[i] = rsqrtf((float)(v + 1));
    s[threadIdx.x] = v;
    __syncthreads();
    for (int off = 1; off < 256; off <<= 1) {
        int t = (threadIdx.x >= off) ? s[threadIdx.x - off] : 0;
        __syncthreads();
        s[threadIdx.x] += t;
        __syncthreads();
    }
    if (i < n) row_ptr[i] = s[threadIdx.x] - v;
    if (threadIdx.x == 255) blksums[blockIdx.x] = s[255];
}

__global__ __launch_bounds__(256) void k_scan2(int* __restrict__ blksums, int nb) {
    __shared__ int s[256];
    int v = (threadIdx.x < nb) ? blksums[threadIdx.x] : 0;
    s[threadIdx.x] = v;
    __syncthreads();
    for (int off = 1; off < 256; off <<= 1) {
        int t = (threadIdx.x >= off) ? s[threadIdx.x - off] : 0;
        __syncthreads();
        s[threadIdx.x] += t;
        __syncthreads();
    }
    if (threadIdx.x < nb) blksums[threadIdx.x] = s[threadIdx.x] - v;
}

__global__ __launch_bounds__(256) void k_scan3(int* __restrict__ row_ptr, const int* __restrict__ blksums,
                                               int n, int ne) {
    int i = blockIdx.x * 256 + threadIdx.x;
    if (i < n) row_ptr[i] += blksums[blockIdx.x];
    if (i == 0) row_ptr[n] = ne;
}

__global__ __launch_bounds__(256) void k_fill(const int* __restrict__ src, const int* __restrict__ dst,
                                              const int* __restrict__ row_ptr, int* __restrict__ cnt,
                                              const float* __restrict__ dinv,
                                              int2* __restrict__ esw, int ne) {
    int e = blockIdx.x * 256 + threadIdx.x;
    if (e < ne) {
        int d = dst[e];
        int s = src[e];
        int pos = row_ptr[d] + atomicSub(&cnt[d], 1) - 1;
        esw[pos] = make_int2(s, __float_as_int(dinv[s]));
    }
}

// ================= W pre-pack: split bf16 hi/lo, B-fragment order, 3 layers =================
__global__ __launch_bounds__(256) void k_prepW(const float* __restrict__ W1, const float* __restrict__ W2,
                                               const float* __restrict__ W3,
                                               uint4* __restrict__ Whi, uint4* __restrict__ Wlo) {
    int idx = blockIdx.x * 256 + threadIdx.x;   // 0..6143
    int layer = idx >> 11;
    const float* W = (layer == 0) ? W1 : (layer == 1) ? W2 : W3;
    int t = idx & 2047;
    int lane = t & 63, sc = t >> 6;
    int s = sc >> 3, c = sc & 7;
    int q = lane >> 4, m = lane & 15;
    int k0 = 32 * s + 8 * q, n0 = 16 * c + m;
    float w[8], h[8];
    #pragma unroll
    for (int j = 0; j < 8; ++j) {
        w[j] = W[(k0 + j) * F + n0];
        h[j] = bf16_rnd(w[j]);
    }
    uint4 uh, ul;
    uh.x = pk_bf16(h[0], h[1]); uh.y = pk_bf16(h[2], h[3]);
    uh.z = pk_bf16(h[4], h[5]); uh.w = pk_bf16(h[6], h[7]);
    ul.x = pk_bf16(w[0] - h[0], w[1] - h[1]); ul.y = pk_bf16(w[2] - h[2], w[3] - h[3]);
    ul.z = pk_bf16(w[4] - h[4], w[5] - h[5]); ul.w = pk_bf16(w[6] - h[6], w[7] - h[7]);
    Whi[idx] = uh;
    Wlo[idx] = ul;
}

// ================= layer-1 GEMM: Tb = bf16(x @ W1), split-bf16 MFMA =================
__global__ __launch_bounds__(256) void k_gemm_mfma(const float* __restrict__ X,
                                                   const uint4* __restrict__ Whi,
                                                   const uint4* __restrict__ Wlo,
                                                   unsigned short* __restrict__ Tb, int n_rows) {
    __shared__ uint4 Wl[4096];   // hi | lo
    int tid = threadIdx.x;
    #pragma unroll
    for (int i = 0; i < 8; ++i) {
        Wl[tid + 256 * i] = Whi[tid + 256 * i];
        Wl[2048 + tid + 256 * i] = Wlo[tid + 256 * i];
    }
    __syncthreads();
    int wave = tid >> 6, lane = tid & 63;
    int q = lane >> 4, m = lane & 15;
    int rowA = blockIdx.x * 64 + wave * 16 + m;
    int rowAc = rowA < n_rows ? rowA : (n_rows - 1);
    f32x4 acc[8];
    #pragma unroll
    for (int c = 0; c < 8; ++c) acc[c] = (f32x4){0.f, 0.f, 0.f, 0.f};
    #pragma unroll
    for (int s = 0; s < 4; ++s) {
        const float* xr = X + (size_t)rowAc * F + 32 * s + 8 * q;
        float4 f0 = ((const float4*)xr)[0];
        float4 f1 = ((const float4*)xr)[1];
        float h0 = bf16_rnd(f0.x), h1 = bf16_rnd(f0.y), h2 = bf16_rnd(f0.z), h3 = bf16_rnd(f0.w);
        float h4 = bf16_rnd(f1.x), h5 = bf16_rnd(f1.y), h6 = bf16_rnd(f1.z), h7 = bf16_rnd(f1.w);
        U4H8 ahi, alo;
        ahi.u.x = (__float_as_uint(h0) >> 16) | (__float_as_uint(h1) & 0xffff0000u);
        ahi.u.y = (__float_as_uint(h2) >> 16) | (__float_as_uint(h3) & 0xffff0000u);
        ahi.u.z = (__float_as_uint(h4) >> 16) | (__float_as_uint(h5) & 0xffff0000u);
        ahi.u.w = (__float_as_uint(h6) >> 16) | (__float_as_uint(h7) & 0xffff0000u);
        alo.u.x = pk_bf16(f0.x - h0, f0.y - h1);
        alo.u.y = pk_bf16(f0.z - h2, f0.w - h3);
        alo.u.z = pk_bf16(f1.x - h4, f1.y - h5);
        alo.u.w = pk_bf16(f1.z - h6, f1.w - h7);
        #pragma unroll
        for (int c = 0; c < 8; ++c) {
            U4H8 bh, bl;
            bh.u = Wl[(s * 8 + c) * 64 + lane];
            bl.u = Wl[2048 + (s * 8 + c) * 64 + lane];
            acc[c] = __builtin_amdgcn_mfma_f32_16x16x32_bf16(ahi.h, bh.h, acc[c], 0, 0, 0);
            acc[c] = __builtin_amdgcn_mfma_f32_16x16x32_bf16(alo.h, bh.h, acc[c], 0, 0, 0);
            acc[c] = __builtin_amdgcn_mfma_f32_16x16x32_bf16(ahi.h, bl.h, acc[c], 0, 0, 0);
        }
    }
    int outr0 = blockIdx.x * 64 + wave * 16 + 4 * q;
    #pragma unroll
    for (int c = 0; c < 8; ++c) {
        #pragma unroll
        for (int r = 0; r < 4; ++r) {
            int rr = outr0 + r;
            if (rr < n_rows) Tb[(size_t)rr * F + 16 * c + m] = bf16_1(acc[c][r]);
        }
    }
}

// ============ layer-1 gather: reads bf16 Tb, writes bf16 H ============
__global__ __launch_bounds__(256) void k_gather(const int* __restrict__ row_ptr,
                                                const int2* __restrict__ esw,
                                                const float* __restrict__ dinv,
                                                const unsigned short* __restrict__ Tb,
                                                const float* __restrict__ bias,
                                                unsigned short* __restrict__ Hb, int n) {
    int grp = threadIdx.x >> 4;
    int node = blockIdx.x * 16 + grp;
    if (node >= n) return;
    int sub = threadIdx.x & 15;
    int beg = row_ptr[node], end = row_ptr[node + 1];
    float dd = dinv[node];

    float4 accL = make_float4(0.f, 0.f, 0.f, 0.f);
    float4 accH = make_float4(0.f, 0.f, 0.f, 0.f);

    for (int chunk = beg; chunk <= end; chunk += 16) {
        int e = chunk + sub;
        int2 rec;
        if (e < end)       rec = esw[e];
        else if (e == end) rec = make_int2(node, __float_as_int(dd));
        else               rec = make_int2(node, 0);

        uint4 rows[16];
        #pragma unroll
        for (int j = 0; j < 16; ++j) {
            int sj = __shfl(rec.x, j, 16);
            rows[j] = ((const uint4*)(Tb + (size_t)sj * F))[sub];
        }
        #pragma unroll
        for (int j = 0; j < 16; ++j) {
            float wj = __uint_as_float((unsigned)__shfl(rec.y, j, 16)) * dd;
            accL.x = fmaf(BF_LO(rows[j].x), wj, accL.x);
            accL.y = fmaf(BF_HI(rows[j].x), wj, accL.y);
            accL.z = fmaf(BF_LO(rows[j].y), wj, accL.z);
            accL.w = fmaf(BF_HI(rows[j].y), wj, accL.w);
            accH.x = fmaf(BF_LO(rows[j].z), wj, accH.x);
            accH.y = fmaf(BF_HI(rows[j].z), wj, accH.y);
            accH.z = fmaf(BF_LO(rows[j].w), wj, accH.z);
            accH.w = fmaf(BF_HI(rows[j].w), wj, accH.w);
        }
    }

    const float4* bb = (const float4*)(bias + sub * 8);
    float4 b0 = bb[0], b1 = bb[1];
    uint4 o;
    o.x = pk_bf16(fmaxf(accL.x + b0.x, 0.f), fmaxf(accL.y + b0.y, 0.f));
    o.y = pk_bf16(fmaxf(accL.z + b0.z, 0.f), fmaxf(accL.w + b0.w, 0.f));
    o.z = pk_bf16(fmaxf(accH.x + b1.x, 0.f), fmaxf(accH.y + b1.y, 0.f));
    o.w = pk_bf16(fmaxf(accH.z + b1.z, 0.f), fmaxf(accH.w + b1.w, 0.f));
    ((uint4*)(Hb + (size_t)node * F))[sub] = o;
}

// ============ fused aggregate-first layer: Hout = bf16(relu(Agg(Hin) @ W + b)) ============
// Block = 64 nodes. Phase 1: 16 groups x 16 lanes gather bf16 Hin rows -> fp32 G in LDS.
// Phase 2: split-bf16 MFMA on G (A) x W (B streamed from L2). Epilogue transposes via G.
#define GP 132   // padded G row stride (floats)
__global__ __launch_bounds__(256) void k_fused(const int* __restrict__ row_ptr,
                                               const int2* __restrict__ esw,
                                               const float* __restrict__ dinv,
                                               const unsigned short* __restrict__ Hin,
                                               const uint4* __restrict__ Whi,
                                               const uint4* __restrict__ Wlo,
                                               const float* __restrict__ bias,
                                               unsigned short* __restrict__ Hout, int n) {
    __shared__ float G[64 * GP];   // 33.8 KB
    int tid = threadIdx.x;
    int d0 = blockIdx.x * 64;
    int grp = tid >> 4, sub = tid & 15;

    // ---- phase 1: gather; group handles local nodes 4*grp .. 4*grp+3 ----
    for (int i = 0; i < 4; ++i) {
        int nl = 4 * grp + i;
        int node = d0 + nl;
        float4 accL = make_float4(0.f, 0.f, 0.f, 0.f);
        float4 accH = make_float4(0.f, 0.f, 0.f, 0.f);
        if (node < n) {
            int beg = row_ptr[node], end = row_ptr[node + 1];
            float dd = dinv[node];
            for (int chunk = beg; chunk <= end; chunk += 16) {
                int e = chunk + sub;
                int2 rec;
                if (e < end)       rec = esw[e];
                else if (e == end) rec = make_int2(node, __float_as_int(dd));
                else               rec = make_int2(node, 0);
                uint4 rows[16];
                #pragma unroll
                for (int j = 0; j < 16; ++j) {
                    int sj = __shfl(rec.x, j, 16);
                    rows[j] = ((const uint4*)(Hin + (size_t)sj * F))[sub];
                }
                #pragma unroll
                for (int j = 0; j < 16; ++j) {
                    float wj = __uint_as_float((unsigned)__shfl(rec.y, j, 16)) * dd;
                    accL.x = fmaf(BF_LO(rows[j].x), wj, accL.x);
                    accL.y = fmaf(BF_HI(rows[j].x), wj, accL.y);
                    accL.z = fmaf(BF_LO(rows[j].y), wj, accL.z);
                    accL.w = fmaf(BF_HI(rows[j].y), wj, accL.w);
                    accH.x = fmaf(BF_LO(rows[j].z), wj, accH.x);
                    accH.y = fmaf(BF_HI(rows[j].z), wj, accH.y);
                    accH.z = fmaf(BF_LO(rows[j].w), wj, accH.z);
                    accH.w = fmaf(BF_HI(rows[j].w), wj, accH.w);
                }
            }
            float* gr = &G[nl * GP + 8 * sub];
            ((float4*)gr)[0] = accL;
            ((float4*)gr)[1] = accH;
        }
    }
    __syncthreads();

    // ---- phase 2: MFMA. wave wv owns rows [16wv, 16wv+16) ----
    int wave = tid >> 6, lane = tid & 63;
    int q = lane >> 4, m = lane & 15;
    f32x4 acc[8];
    #pragma unroll
    for (int c = 0; c < 8; ++c) acc[c] = (f32x4){0.f, 0.f, 0.f, 0.f};
    #pragma unroll
    for (int s = 0; s < 4; ++s) {
        const float* gr = &G[(16 * wave + m) * GP + 32 * s + 8 * q];
        float4 f0 = ((const float4*)gr)[0];
        float4 f1 = ((const float4*)gr)[1];
        float h0 = bf16_rnd(f0.x), h1 = bf16_rnd(f0.y), h2 = bf16_rnd(f0.z), h3 = bf16_rnd(f0.w);
        float h4 = bf16_rnd(f1.x), h5 = bf16_rnd(f1.y), h6 = bf16_rnd(f1.z), h7 = bf16_rnd(f1.w);
        U4H8 ahi, alo;
        ahi.u.x = (__float_as_uint(h0) >> 16) | (__float_as_uint(h1) & 0xffff0000u);
        ahi.u.y = (__float_as_uint(h2) >> 16) | (__float_as_uint(h3) & 0xffff0000u);
        ahi.u.z = (__float_as_uint(h4) >> 16) | (__float_as_uint(h5) & 0xffff0000u);
        ahi.u.w = (__float_as_uint(h6) >> 16) | (__float_as_uint(h7) & 0xffff0000u);
        alo.u.x = pk_bf16(f0.x - h0, f0.y - h1);
        alo.u.y = pk_bf16(f0.z - h2, f0.w - h3);
        alo.u.z = pk_bf16(f1.x - h4, f1.y - h5);
        alo.u.w = pk_bf16(f1.z - h6, f1.w - h7);
        #pragma unroll
        for (int c = 0; c < 8; ++c) {
            U4H8 bh, bl;
            bh.u = Whi[(s * 8 + c) * 64 + lane];
            bl.u = Wlo[(s * 8 + c) * 64 + lane];
            acc[c] = __builtin_amdgcn_mfma_f32_16x16x32_bf16(ahi.h, bh.h, acc[c], 0, 0, 0);
            acc[c] = __builtin_amdgcn_mfma_f32_16x16x32_bf16(alo.h, bh.h, acc[c], 0, 0, 0);
            acc[c] = __builtin_amdgcn_mfma_f32_16x16x32_bf16(ahi.h, bl.h, acc[c], 0, 0, 0);
        }
    }
    __syncthreads();   // done reading G

    // ---- epilogue: bias + relu -> G (transpose), then coalesced bf16 store ----
    #pragma unroll
    for (int c = 0; c < 8; ++c) {
        float bb = bias[16 * c + m];
        #pragma unroll
        for (int r = 0; r < 4; ++r)
            G[(16 * wave + 4 * q + r) * GP + 16 * c + m] = fmaxf(acc[c][r] + bb, 0.f);
    }
    __syncthreads();
    #pragma unroll
    for (int j = 0; j < 4; ++j) {
        int lin = tid + 256 * j;          // uint4 index: 16 per row
        int row = lin >> 4, c8 = lin & 15;
        int node = d0 + row;
        if (node < n) {
            const float* gr = &G[row * GP + c8 * 8];
            uint4 o;
            o.x = pk_bf16(gr[0], gr[1]);
            o.y = pk_bf16(gr[2], gr[3]);
            o.z = pk_bf16(gr[4], gr[5]);
            o.w = pk_bf16(gr[6], gr[7]);
            ((uint4*)(Hout + (size_t)node * F))[c8] = o;
        }
    }
}

// ============ fused pool (segment mean, bf16 in) + FC head ============
__global__ __launch_bounds__(256) void k_pool_fc(const unsigned short* __restrict__ Hb,
                                                 const int* __restrict__ batch,
                                                 const float* __restrict__ Wf1,
                                                 const float* __restrict__ bf1,
                                                 const float* __restrict__ Wf2,
                                                 const float* __restrict__ bf2,
                                                 float* __restrict__ out) {
    int g = blockIdx.x;
    int tid = threadIdx.x;
    int lo = 0, hi = N_NODES;
    while (lo < hi) { int mid = (lo + hi) >> 1; if (batch[mid] < g) lo = mid + 1; else hi = mid; }
    int start = lo;
    hi = N_NODES;
    while (lo < hi) { int mid = (lo + hi) >> 1; if (batch[mid] <= g) lo = mid + 1; else hi = mid; }
    int end = lo;

    __shared__ float hs[4][F];
    __shared__ float hg[F];
    int wv = tid >> 6, lane = tid & 63;
    int half = lane >> 5, sub = lane & 31;
    float4 a = make_float4(0.f, 0.f, 0.f, 0.f);
    for (int i = start + wv * 2 + half; i < end; i += 8) {
        uint2 v = ((const uint2*)(Hb + (size_t)i * F))[sub];
        a.x += BF_LO(v.x); a.y += BF_HI(v.x);
        a.z += BF_LO(v.y); a.w += BF_HI(v.y);
    }
    a.x += __shfl_xor(a.x, 32, 64);
    a.y += __shfl_xor(a.y, 32, 64);
    a.z += __shfl_xor(a.z, 32, 64);
    a.w += __shfl_xor(a.w, 32, 64);
    if (half == 0) ((float4*)hs[wv])[sub] = a;
    __syncthreads();
    if (tid < F) {
        float inv = 1.0f / (float)((end - start) > 0 ? (end - start) : 1);
        hg[tid] = (hs[0][tid] + hs[1][tid] + hs[2][tid] + hs[3][tid]) * inv;
    }
    __syncthreads();
    if (tid < 64) {
        float acc = bf1[tid];
        #pragma unroll 4
        for (int f = 0; f < F; ++f) acc = fmaf(hg[f], Wf1[f * 64 + tid], acc);
        float v = fmaxf(acc, 0.f) * Wf2[tid];
        #pragma unroll
        for (int off = 32; off > 0; off >>= 1) v += __shfl_down(v, off, 64);
        if (tid == 0) out[g] = v + bf2[0];
    }
}

extern "C" void kernel_launch(void* const* d_in, const int* in_sizes, int n_in,
                              void* d_out, int out_size, void* d_ws, size_t ws_size,
                              hipStream_t stream) {
    const float* x    = (const float*)d_in[0];
    const int* eidx   = (const int*)d_in[1];
    const int* batch  = (const int*)d_in[2];
    const float* W1   = (const float*)d_in[3];
    const float* b1   = (const float*)d_in[4];
    const float* W2   = (const float*)d_in[5];
    const float* b2   = (const float*)d_in[6];
    const float* W3   = (const float*)d_in[7];
    const float* b3   = (const float*)d_in[8];
    const float* Wf1  = (const float*)d_in[9];
    const float* bf1  = (const float*)d_in[10];
    const float* Wf2  = (const float*)d_in[11];
    const float* bf2  = (const float*)d_in[12];
    float* out = (float*)d_out;

    const int* src = eidx;
    const int* dst = eidx + N_EDGES;

    char* p = (char*)d_ws;
    unsigned short* Tb  = (unsigned short*)p;  p += (size_t)N_NODES * F * 2;
    unsigned short* H1  = (unsigned short*)p;  p += (size_t)N_NODES * F * 2;
    unsigned short* H2  = (unsigned short*)p;  p += (size_t)N_NODES * F * 2;
    unsigned short* H3  = (unsigned short*)p;  p += (size_t)N_NODES * F * 2;
    int2* esw   = (int2*)p;    p += (size_t)N_EDGES * sizeof(int2);
    uint4* Whi  = (uint4*)p;   p += (size_t)3 * 2048 * sizeof(uint4);
    uint4* Wlo  = (uint4*)p;   p += (size_t)3 * 2048 * sizeof(uint4);
    float* dinv = (float*)p;   p += (size_t)N_NODES * sizeof(float);
    int* cnt     = (int*)p;    p += (size_t)N_NODES * sizeof(int);
    int* row_ptr = (int*)p;    p += (size_t)(N_NODES + 1) * sizeof(int);
    int* blksums = (int*)p;    p += 256 * sizeof(int);

    dim3 b256(256);
    int gNodes   = (N_NODES + 255) / 256;
    int gEdges   = (N_EDGES + 255) / 256;
    int gGemm    = (N_NODES + 63) / 64;      // 782
    int gGather  = (N_NODES + 15) / 16;      // 3125
    int gFused   = (N_NODES + 63) / 64;      // 782

    // ---- W pre-pack ----
    k_prepW<<<24, b256, 0, stream>>>(W1, W2, W3, Whi, Wlo);

    // ---- CSR build ----
    hipMemsetAsync(cnt, 0, (size_t)N_NODES * sizeof(int), stream);
    k_hist<<<gEdges, b256, 0, stream>>>(dst, cnt, N_EDGES);
    k_scan1<<<gNodes, b256, 0, stream>>>(cnt, row_ptr, blksums, dinv, N_NODES);
    k_scan2<<<1, b256, 0, stream>>>(blksums, gNodes);
    k_scan3<<<gNodes, b256, 0, stream>>>(row_ptr, blksums, N_NODES, N_EDGES);
    k_fill<<<gEdges, b256, 0, stream>>>(src, dst, row_ptr, cnt, dinv, esw, N_EDGES);

    // ---- layer 1 (transform-first): x -> Tb -> H1 ----
    k_gemm_mfma<<<gGemm, b256, 0, stream>>>(x, Whi, Wlo, Tb, N_NODES);
    k_gather<<<gGather, b256, 0, stream>>>(row_ptr, esw, dinv, Tb, b1, H1, N_NODES);

    // ---- layer 2 (aggregate-first, fused): H1 -> H2 ----
    k_fused<<<gFused, b256, 0, stream>>>(row_ptr, esw, dinv, H1, Whi + 2048, Wlo + 2048, b2, H2, N_NODES);

    // ---- layer 3 (aggregate-first, fused): H2 -> H3 ----
    k_fused<<<gFused, b256, 0, stream>>>(row_ptr, esw, dinv, H2, Whi + 4096, Wlo + 4096, b3, H3, N_NODES);

    // ---- pool + FC ----
    k_pool_fc<<<N_GRAPHS, b256, 0, stream>>>(H3, batch, Wf1, bf1, Wf2, bf2, out);
}

// Round 10
// 292.029 us; speedup vs baseline: 6.1559x; 1.0139x over previous
//
#include <hip/hip_runtime.h>

#define N_NODES 50000
#define N_EDGES 600000
#define N_GRAPHS 500
#define F 128

typedef short bf16x8 __attribute__((ext_vector_type(8)));
typedef float f32x4 __attribute__((ext_vector_type(4)));
union U4H8 { uint4 u; bf16x8 h; };

// ---- bf16 helpers (RNE) ----
__device__ inline unsigned pk_bf16(float a, float b) {
    unsigned ua = __float_as_uint(a), ub = __float_as_uint(b);
    ua = (ua + 0x7fffu + ((ua >> 16) & 1u)) >> 16;
    ub = (ub + 0x7fffu + ((ub >> 16) & 1u)) >> 16;
    return ua | (ub << 16);
}
__device__ inline float bf16_rnd(float x) {
    unsigned u = __float_as_uint(x);
    u = (u + 0x7fffu + ((u >> 16) & 1u)) & 0xffff0000u;
    return __uint_as_float(u);
}
#define BF_LO(u) __uint_as_float((u) << 16)
#define BF_HI(u) __uint_as_float((u) & 0xffff0000u)

// ================= x -> bf16 =================
__global__ __launch_bounds__(256) void k_cvt(const float* __restrict__ x,
                                             unsigned short* __restrict__ xb, int n8) {
    int idx = blockIdx.x * 256 + threadIdx.x;
    if (idx < n8) {
        const float4* xr = (const float4*)(x + (size_t)idx * 8);
        float4 a = xr[0], b = xr[1];
        uint4 o;
        o.x = pk_bf16(a.x, a.y); o.y = pk_bf16(a.z, a.w);
        o.z = pk_bf16(b.x, b.y); o.w = pk_bf16(b.z, b.w);
        ((uint4*)xb)[idx] = o;
    }
}

// ================= CSR build =================
__global__ __launch_bounds__(256) void k_hist(const int* __restrict__ dst, int* __restrict__ cnt, int ne) {
    int e = blockIdx.x * 256 + threadIdx.x;
    if (e < ne) atomicAdd(&cnt[dst[e]], 1);
}

__global__ __launch_bounds__(256) void k_scan1(const int* __restrict__ cnt, int* __restrict__ row_ptr,
                                               int* __restrict__ blksums, float* __restrict__ dinv, int n) {
    __shared__ int s[256];
    int i = blockIdx.x * 256 + threadIdx.x;
    int v = (i < n) ? cnt[i] : 0;
    if (i < n) dinv[i] = rsqrtf((float)(v + 1));
    s[threadIdx.x] = v;
    __syncthreads();
    for (int off = 1; off < 256; off <<= 1) {
        int t = (threadIdx.x >= off) ? s[threadIdx.x - off] : 0;
        __syncthreads();
        s[threadIdx.x] += t;
        __syncthreads();
    }
    if (i < n) row_ptr[i] = s[threadIdx.x] - v;
    if (threadIdx.x == 255) blksums[blockIdx.x] = s[255];
}

__global__ __launch_bounds__(256) void k_scan2(int* __restrict__ blksums, int nb) {
    __shared__ int s[256];
    int v = (threadIdx.x < nb) ? blksums[threadIdx.x] : 0;
    s[threadIdx.x] = v;
    __syncthreads();
    for (int off = 1; off < 256; off <<= 1) {
        int t = (threadIdx.x >= off) ? s[threadIdx.x - off] : 0;
        __syncthreads();
        s[threadIdx.x] += t;
        __syncthreads();
    }
    if (threadIdx.x < nb) blksums[threadIdx.x] = s[threadIdx.x] - v;
}

__global__ __launch_bounds__(256) void k_scan3(int* __restrict__ row_ptr, const int* __restrict__ blksums,
                                               int n, int ne) {
    int i = blockIdx.x * 256 + threadIdx.x;
    if (i < n) row_ptr[i] += blksums[blockIdx.x];
    if (i == 0) row_ptr[n] = ne;
}

__global__ __launch_bounds__(256) void k_fill(const int* __restrict__ src, const int* __restrict__ dst,
                                              const int* __restrict__ row_ptr, int* __restrict__ cnt,
                                              const float* __restrict__ dinv,
                                              int2* __restrict__ esw, int ne) {
    int e = blockIdx.x * 256 + threadIdx.x;
    if (e < ne) {
        int d = dst[e];
        int s = src[e];
        int pos = row_ptr[d] + atomicSub(&cnt[d], 1) - 1;
        esw[pos] = make_int2(s, __float_as_int(dinv[s]));
    }
}

// ================= W pre-pack: split bf16 hi/lo, B-fragment order, 3 layers =================
__global__ __launch_bounds__(256) void k_prepW(const float* __restrict__ W1, const float* __restrict__ W2,
                                               const float* __restrict__ W3,
                                               uint4* __restrict__ Whi, uint4* __restrict__ Wlo) {
    int idx = blockIdx.x * 256 + threadIdx.x;   // 0..6143
    int layer = idx >> 11;
    const float* W = (layer == 0) ? W1 : (layer == 1) ? W2 : W3;
    int t = idx & 2047;
    int lane = t & 63, sc = t >> 6;
    int s = sc >> 3, c = sc & 7;
    int q = lane >> 4, m = lane & 15;
    int k0 = 32 * s + 8 * q, n0 = 16 * c + m;
    float w[8], h[8];
    #pragma unroll
    for (int j = 0; j < 8; ++j) {
        w[j] = W[(k0 + j) * F + n0];
        h[j] = bf16_rnd(w[j]);
    }
    uint4 uh, ul;
    uh.x = pk_bf16(h[0], h[1]); uh.y = pk_bf16(h[2], h[3]);
    uh.z = pk_bf16(h[4], h[5]); uh.w = pk_bf16(h[6], h[7]);
    ul.x = pk_bf16(w[0] - h[0], w[1] - h[1]); ul.y = pk_bf16(w[2] - h[2], w[3] - h[3]);
    ul.z = pk_bf16(w[4] - h[4], w[5] - h[5]); ul.w = pk_bf16(w[6] - h[6], w[7] - h[7]);
    Whi[idx] = uh;
    Wlo[idx] = ul;
}

// ============ fused aggregate-first layer: Hout = bf16(relu(Agg(Hin) @ W + b)) ============
// 32-node tile. Phase 1: 16 groups x 16 lanes gather bf16 rows -> fp32 G (LDS, 16.9 KB).
// Phase 2: wave = (row-tile, col-half): rt=wave&1 rows 16rt.., cols 4*(wave>>1)..+3;
//          split-bf16 MFMA, W streamed from L2. Epilogue transposes via G.
#define TN 32
#define GP 132
__global__ __launch_bounds__(256) void k_fused(const int* __restrict__ row_ptr,
                                               const int2* __restrict__ esw,
                                               const float* __restrict__ dinv,
                                               const unsigned short* __restrict__ Hin,
                                               const uint4* __restrict__ Whi,
                                               const uint4* __restrict__ Wlo,
                                               const float* __restrict__ bias,
                                               unsigned short* __restrict__ Hout, int n) {
    __shared__ float G[TN * GP];
    int tid = threadIdx.x;
    int d0 = blockIdx.x * TN;
    int grp = tid >> 4, sub = tid & 15;

    // ---- phase 1: group handles local nodes 2*grp, 2*grp+1 ----
    #pragma unroll
    for (int i = 0; i < 2; ++i) {
        int nl = 2 * grp + i;
        int node = d0 + nl;
        float4 accL = make_float4(0.f, 0.f, 0.f, 0.f);
        float4 accH = make_float4(0.f, 0.f, 0.f, 0.f);
        if (node < n) {
            int beg = row_ptr[node], end = row_ptr[node + 1];
            float dd = dinv[node];
            for (int chunk = beg; chunk <= end; chunk += 16) {
                int e = chunk + sub;
                int2 rec;
                if (e < end)       rec = esw[e];
                else if (e == end) rec = make_int2(node, __float_as_int(dd));
                else               rec = make_int2(node, 0);
                uint4 rows[16];
                #pragma unroll
                for (int j = 0; j < 16; ++j) {
                    int sj = __shfl(rec.x, j, 16);
                    rows[j] = ((const uint4*)(Hin + (size_t)sj * F))[sub];
                }
                #pragma unroll
                for (int j = 0; j < 16; ++j) {
                    float wj = __uint_as_float((unsigned)__shfl(rec.y, j, 16)) * dd;
                    accL.x = fmaf(BF_LO(rows[j].x), wj, accL.x);
                    accL.y = fmaf(BF_HI(rows[j].x), wj, accL.y);
                    accL.z = fmaf(BF_LO(rows[j].y), wj, accL.z);
                    accL.w = fmaf(BF_HI(rows[j].y), wj, accL.w);
                    accH.x = fmaf(BF_LO(rows[j].z), wj, accH.x);
                    accH.y = fmaf(BF_HI(rows[j].z), wj, accH.y);
                    accH.z = fmaf(BF_LO(rows[j].w), wj, accH.z);
                    accH.w = fmaf(BF_HI(rows[j].w), wj, accH.w);
                }
            }
        }
        float* gr = &G[nl * GP + 8 * sub];
        ((float4*)gr)[0] = accL;
        ((float4*)gr)[1] = accH;
    }
    __syncthreads();

    // ---- phase 2: MFMA ----
    int wave = tid >> 6, lane = tid & 63;
    int q = lane >> 4, m = lane & 15;
    int rt = wave & 1;            // row tile: rows 16rt..16rt+15
    int ch = (wave >> 1) * 4;     // col tiles ch..ch+3
    int row0 = 16 * rt;
    f32x4 acc[4];
    #pragma unroll
    for (int c = 0; c < 4; ++c) acc[c] = (f32x4){0.f, 0.f, 0.f, 0.f};
    #pragma unroll
    for (int s = 0; s < 4; ++s) {
        const float* gr = &G[(row0 + m) * GP + 32 * s + 8 * q];
        float4 f0 = ((const float4*)gr)[0];
        float4 f1 = ((const float4*)gr)[1];
        float h0 = bf16_rnd(f0.x), h1 = bf16_rnd(f0.y), h2 = bf16_rnd(f0.z), h3 = bf16_rnd(f0.w);
        float h4 = bf16_rnd(f1.x), h5 = bf16_rnd(f1.y), h6 = bf16_rnd(f1.z), h7 = bf16_rnd(f1.w);
        U4H8 ahi, alo;
        ahi.u.x = (__float_as_uint(h0) >> 16) | (__float_as_uint(h1) & 0xffff0000u);
        ahi.u.y = (__float_as_uint(h2) >> 16) | (__float_as_uint(h3) & 0xffff0000u);
        ahi.u.z = (__float_as_uint(h4) >> 16) | (__float_as_uint(h5) & 0xffff0000u);
        ahi.u.w = (__float_as_uint(h6) >> 16) | (__float_as_uint(h7) & 0xffff0000u);
        alo.u.x = pk_bf16(f0.x - h0, f0.y - h1);
        alo.u.y = pk_bf16(f0.z - h2, f0.w - h3);
        alo.u.z = pk_bf16(f1.x - h4, f1.y - h5);
        alo.u.w = pk_bf16(f1.z - h6, f1.w - h7);
        #pragma unroll
        for (int cc = 0; cc < 4; ++cc) {
            int c = ch + cc;
            U4H8 bh, bl;
            bh.u = Whi[(s * 8 + c) * 64 + lane];
            bl.u = Wlo[(s * 8 + c) * 64 + lane];
            acc[cc] = __builtin_amdgcn_mfma_f32_16x16x32_bf16(ahi.h, bh.h, acc[cc], 0, 0, 0);
            acc[cc] = __builtin_amdgcn_mfma_f32_16x16x32_bf16(alo.h, bh.h, acc[cc], 0, 0, 0);
            acc[cc] = __builtin_amdgcn_mfma_f32_16x16x32_bf16(ahi.h, bl.h, acc[cc], 0, 0, 0);
        }
    }
    __syncthreads();   // all A reads from G done

    // ---- epilogue: bias + relu -> G (transpose), coalesced bf16 store ----
    #pragma unroll
    for (int cc = 0; cc < 4; ++cc) {
        int c = ch + cc;
        float bb = bias[16 * c + m];
        #pragma unroll
        for (int r = 0; r < 4; ++r)
            G[(row0 + 4 * q + r) * GP + 16 * c + m] = fmaxf(acc[cc][r] + bb, 0.f);
    }
    __syncthreads();
    #pragma unroll
    for (int j = 0; j < 2; ++j) {
        int lin = tid + 256 * j;          // uint4 index: 16 per row, 512 total
        int row = lin >> 4, c8 = lin & 15;
        int node = d0 + row;
        if (node < n) {
            const float* gr = &G[row * GP + c8 * 8];
            uint4 o;
            o.x = pk_bf16(gr[0], gr[1]);
            o.y = pk_bf16(gr[2], gr[3]);
            o.z = pk_bf16(gr[4], gr[5]);
            o.w = pk_bf16(gr[6], gr[7]);
            ((uint4*)(Hout + (size_t)node * F))[c8] = o;
        }
    }
}

// ============ fused pool (segment mean, bf16 in) + FC head ============
__global__ __launch_bounds__(256) void k_pool_fc(const unsigned short* __restrict__ Hb,
                                                 const int* __restrict__ batch,
                                                 const float* __restrict__ Wf1,
                                                 const float* __restrict__ bf1,
                                                 const float* __restrict__ Wf2,
                                                 const float* __restrict__ bf2,
                                                 float* __restrict__ out) {
    int g = blockIdx.x;
    int tid = threadIdx.x;
    int lo = 0, hi = N_NODES;
    while (lo < hi) { int mid = (lo + hi) >> 1; if (batch[mid] < g) lo = mid + 1; else hi = mid; }
    int start = lo;
    hi = N_NODES;
    while (lo < hi) { int mid = (lo + hi) >> 1; if (batch[mid] <= g) lo = mid + 1; else hi = mid; }
    int end = lo;

    __shared__ float hs[4][F];
    __shared__ float hg[F];
    int wv = tid >> 6, lane = tid & 63;
    int half = lane >> 5, sub = lane & 31;
    float4 a = make_float4(0.f, 0.f, 0.f, 0.f);
    for (int i = start + wv * 2 + half; i < end; i += 8) {
        uint2 v = ((const uint2*)(Hb + (size_t)i * F))[sub];
        a.x += BF_LO(v.x); a.y += BF_HI(v.x);
        a.z += BF_LO(v.y); a.w += BF_HI(v.y);
    }
    a.x += __shfl_xor(a.x, 32, 64);
    a.y += __shfl_xor(a.y, 32, 64);
    a.z += __shfl_xor(a.z, 32, 64);
    a.w += __shfl_xor(a.w, 32, 64);
    if (half == 0) ((float4*)hs[wv])[sub] = a;
    __syncthreads();
    if (tid < F) {
        float inv = 1.0f / (float)((end - start) > 0 ? (end - start) : 1);
        hg[tid] = (hs[0][tid] + hs[1][tid] + hs[2][tid] + hs[3][tid]) * inv;
    }
    __syncthreads();
    if (tid < 64) {
        float acc = bf1[tid];
        #pragma unroll 4
        for (int f = 0; f < F; ++f) acc = fmaf(hg[f], Wf1[f * 64 + tid], acc);
        float v = fmaxf(acc, 0.f) * Wf2[tid];
        #pragma unroll
        for (int off = 32; off > 0; off >>= 1) v += __shfl_down(v, off, 64);
        if (tid == 0) out[g] = v + bf2[0];
    }
}

extern "C" void kernel_launch(void* const* d_in, const int* in_sizes, int n_in,
                              void* d_out, int out_size, void* d_ws, size_t ws_size,
                              hipStream_t stream) {
    const float* x    = (const float*)d_in[0];
    const int* eidx   = (const int*)d_in[1];
    const int* batch  = (const int*)d_in[2];
    const float* W1   = (const float*)d_in[3];
    const float* b1   = (const float*)d_in[4];
    const float* W2   = (const float*)d_in[5];
    const float* b2   = (const float*)d_in[6];
    const float* W3   = (const float*)d_in[7];
    const float* b3   = (const float*)d_in[8];
    const float* Wf1  = (const float*)d_in[9];
    const float* bf1  = (const float*)d_in[10];
    const float* Wf2  = (const float*)d_in[11];
    const float* bf2  = (const float*)d_in[12];
    float* out = (float*)d_out;

    const int* src = eidx;
    const int* dst = eidx + N_EDGES;

    char* p = (char*)d_ws;
    unsigned short* Xb  = (unsigned short*)p;  p += (size_t)N_NODES * F * 2;
    unsigned short* H1  = (unsigned short*)p;  p += (size_t)N_NODES * F * 2;
    unsigned short* H2  = (unsigned short*)p;  p += (size_t)N_NODES * F * 2;
    unsigned short* H3  = (unsigned short*)p;  p += (size_t)N_NODES * F * 2;
    int2* esw   = (int2*)p;    p += (size_t)N_EDGES * sizeof(int2);
    uint4* Whi  = (uint4*)p;   p += (size_t)3 * 2048 * sizeof(uint4);
    uint4* Wlo  = (uint4*)p;   p += (size_t)3 * 2048 * sizeof(uint4);
    float* dinv = (float*)p;   p += (size_t)N_NODES * sizeof(float);
    int* cnt     = (int*)p;    p += (size_t)N_NODES * sizeof(int);
    int* row_ptr = (int*)p;    p += (size_t)(N_NODES + 1) * sizeof(int);
    int* blksums = (int*)p;    p += 256 * sizeof(int);

    dim3 b256(256);
    int gNodes = (N_NODES + 255) / 256;
    int gEdges = (N_EDGES + 255) / 256;
    int gCvt   = (N_NODES * F / 8 + 255) / 256;   // 3125
    int gFused = (N_NODES + TN - 1) / TN;         // 1563

    // ---- independent prep ----
    k_cvt<<<gCvt, b256, 0, stream>>>(x, Xb, N_NODES * F / 8);
    k_prepW<<<24, b256, 0, stream>>>(W1, W2, W3, Whi, Wlo);

    // ---- CSR build ----
    hipMemsetAsync(cnt, 0, (size_t)N_NODES * sizeof(int), stream);
    k_hist<<<gEdges, b256, 0, stream>>>(dst, cnt, N_EDGES);
    k_scan1<<<gNodes, b256, 0, stream>>>(cnt, row_ptr, blksums, dinv, N_NODES);
    k_scan2<<<1, b256, 0, stream>>>(blksums, gNodes);
    k_scan3<<<gNodes, b256, 0, stream>>>(row_ptr, blksums, N_NODES, N_EDGES);
    k_fill<<<gEdges, b256, 0, stream>>>(src, dst, row_ptr, cnt, dinv, esw, N_EDGES);

    // ---- 3 aggregate-first fused layers ----
    k_fused<<<gFused, b256, 0, stream>>>(row_ptr, esw, dinv, Xb, Whi,        Wlo,        b1, H1, N_NODES);
    k_fused<<<gFused, b256, 0, stream>>>(row_ptr, esw, dinv, H1, Whi + 2048, Wlo + 2048, b2, H2, N_NODES);
    k_fused<<<gFused, b256, 0, stream>>>(row_ptr, esw, dinv, H2, Whi + 4096, Wlo + 4096, b3, H3, N_NODES);

    // ---- pool + FC ----
    k_pool_fc<<<N_GRAPHS, b256, 0, stream>>>(H3, batch, Wf1, bf1, Wf2, bf2, out);
}